// Round 9
// baseline (360.501 us; speedup 1.0000x reference)
//
#include <hip/hip_runtime.h>
#include <math.h>

#define NNODES 50000
#define NEDGES 800000
#define MPAD   50048   // NNODES rounded up to 128
#define NBLK   196     // ceil(NNODES/256)
#define PREP_XBLK 3128 // MPAD*128/8/256  (8 floats per thread)
#define PREP_TBLK 64   // 64x64 transpose tiles (32 for wt1, 32 for wt2)
#define CNT2_BLK  1563 // ceil(NEDGES/512) (2 edges per thread)
#define CNT_BLK   3125 // NEDGES/256

typedef __bf16 bf16_t;
typedef unsigned char u8;
typedef __attribute__((ext_vector_type(8))) __bf16 bf16x8;
typedef __attribute__((ext_vector_type(4))) float  floatx4;
typedef __attribute__((ext_vector_type(2))) float  floatx2;

__device__ __forceinline__ float bf_lo(unsigned u) { return __uint_as_float(u << 16); }
__device__ __forceinline__ float bf_hi(unsigned u) { return __uint_as_float(u & 0xffff0000u); }

__device__ __forceinline__ void gload_lds16(const bf16_t* g, bf16_t* l) {
    __builtin_amdgcn_global_load_lds(
        (const __attribute__((address_space(1))) unsigned int*)g,
        (__attribute__((address_space(3))) unsigned int*)l, 16, 0, 0);
}

// DPP-based partial-sum: x += x[from dpp_ctrl permutation]; pure VALU (no ds_bpermute).
// 0xB1 = quad_perm[1,0,3,2] (xor1), 0x4E = quad_perm[2,3,0,1] (xor2),
// 0x124 = row_ror:4, 0x128 = row_ror:8 (valid for sums once values are quad-constant).
template <int CTRL>
__device__ __forceinline__ float dpp_radd(float x) {
    int y = __builtin_amdgcn_update_dpp(0, __float_as_int(x), CTRL, 0xf, 0xf, true);
    return x + __int_as_float(y);
}

struct W4 { const float* W[4]; };

// ---- prep: x cast (8/thread) + LDS-tiled weight transpose (no atomics here) ----
__global__ void prep_kernel(const float* __restrict__ x, W4 w1, W4 w2,
                            bf16_t* __restrict__ xb, bf16_t* __restrict__ wt1,
                            bf16_t* __restrict__ wt2) {
    int b = blockIdx.x;
    if (b < PREP_XBLK) {
        int i = (b * 256 + threadIdx.x) * 8;      // 8 floats; never straddles a row
        int row = i >> 7;
        bf16_t r[8];
        if (row < NNODES) {
            float4 v0 = *(const float4*)(x + i);
            float4 v1 = *(const float4*)(x + i + 4);
            r[0] = (bf16_t)v0.x; r[1] = (bf16_t)v0.y; r[2] = (bf16_t)v0.z; r[3] = (bf16_t)v0.w;
            r[4] = (bf16_t)v1.x; r[5] = (bf16_t)v1.y; r[6] = (bf16_t)v1.z; r[7] = (bf16_t)v1.w;
        } else {
            #pragma unroll
            for (int j = 0; j < 8; j++) r[j] = (bf16_t)0.f;
        }
        *(uint4*)(xb + i) = *(uint4*)r;
    } else {
        // 64x64 tile transpose via LDS: coalesced reads AND writes
        __shared__ float tile[64][65];
        int tau = b - PREP_XBLK;
        const float* Wsrc; bf16_t* dstp; int srcld, dstld, k0, c0;
        if (tau < 32) {            // wt1: four 128x256 matrices -> [c][k]
            int m = tau >> 3, sub = tau & 7;
            k0 = (sub >> 2) * 64;  c0 = (sub & 3) * 64;
            Wsrc = w1.W[m]; srcld = 256;
            dstp = wt1 + (size_t)(m * 256 + c0) * 128 + k0; dstld = 128;
        } else {                   // wt2: four 256x128 matrices -> [c][k]
            int t2 = tau - 32;
            int m = t2 >> 3, sub = t2 & 7;
            k0 = (sub >> 1) * 64;  c0 = (sub & 1) * 64;
            Wsrc = w2.W[m]; srcld = 128;
            dstp = wt2 + (size_t)(m * 128 + c0) * 256 + k0; dstld = 256;
        }
        int wv = threadIdx.x >> 6, ln = threadIdx.x & 63;
        #pragma unroll
        for (int rr = 0; rr < 16; rr++) {
            int row = wv * 16 + rr;
            tile[row][ln] = Wsrc[(size_t)(k0 + row) * srcld + c0 + ln];
        }
        __syncthreads();
        #pragma unroll
        for (int rr = 0; rr < 16; rr++) {
            int col = wv * 16 + rr;
            dstp[(size_t)col * dstld + ln] = (bf16_t)tile[ln][col];   // conflict-free: (ln+col)%32
        }
    }
}

// ---- dedicated count: 2 independent returning atomics per thread, zero LDS ----
// Grid 1563 blocks -> ~6 blocks/CU resident -> ~48 in-flight atomics/CU.
__global__ void count_kernel(const int* __restrict__ dst, int* __restrict__ deg,
                             int* __restrict__ pack) {
    int e0 = blockIdx.x * 512 + threadIdx.x;
    int e1 = e0 + 256;
    int d0 = (e0 < NEDGES) ? dst[e0] : -1;
    int d1 = (e1 < NEDGES) ? dst[e1] : -1;
    int o0 = 0, o1 = 0;
    if (d0 >= 0) o0 = atomicAdd(&deg[d0], 1);   // independent, both in flight
    if (d1 >= 0) o1 = atomicAdd(&deg[d1], 1);
    if (d0 >= 0) pack[e0] = (o0 << 16) | d0;    // dst < 50000 < 2^16
    if (d1 >= 0) pack[e1] = (o1 << 16) | d1;
}

// ---------------- CSR scan (separate kernels, full parallelism) ----------------
__global__ void blocksum_kernel(const int* __restrict__ deg, int* __restrict__ psum) {
    int t = threadIdx.x;
    int i = blockIdx.x * 256 + t;
    int v = (i < NNODES) ? deg[i] : 0;
    __shared__ int s[256];
    s[t] = v;
    __syncthreads();
    for (int off = 128; off; off >>= 1) {
        if (t < off) s[t] += s[t + off];
        __syncthreads();
    }
    if (t == 0) psum[blockIdx.x] = s[0];
}

__global__ void scanpart_kernel(int* __restrict__ psum) {
    __shared__ int s[256];
    int t = threadIdx.x;
    int v = (t < NBLK) ? psum[t] : 0;
    s[t] = v;
    __syncthreads();
    for (int off = 1; off < 256; off <<= 1) {
        int val = (t >= off) ? s[t - off] : 0;
        __syncthreads();
        s[t] += val;
        __syncthreads();
    }
    if (t < NBLK) psum[t] = s[t] - v;   // exclusive
}

__global__ void scanfinal_kernel(const int* __restrict__ deg, const int* __restrict__ psum,
                                 int* __restrict__ row_ptr) {
    int t = threadIdx.x;
    int b = blockIdx.x;
    int i = b * 256 + t;
    int v = (i < NNODES) ? deg[i] : 0;
    __shared__ int s[256];
    s[t] = v;
    __syncthreads();
    for (int off = 1; off < 256; off <<= 1) {
        int val = (t >= off) ? s[t - off] : 0;
        __syncthreads();
        s[t] += val;
        __syncthreads();
    }
    if (i <= NNODES) row_ptr[i] = psum[b] + s[t] - v;  // exclusive prefix
}

// atomic-free scatter: slot = row_ptr[dst] + ordinal
__global__ void scatter_kernel(const int* __restrict__ src, const int* __restrict__ pack,
                               const int* __restrict__ row_ptr, int* __restrict__ esrc) {
    int e = blockIdx.x * 256 + threadIdx.x;
    if (e >= NEDGES) return;
    int p = pack[e];
    int d = p & 0xFFFF;
    int ord = p >> 16;
    esrc[row_ptr[d] + ord] = src[e];
}

// ---------------- bf16 MFMA GEMM: C_mat = (A @ W_mat + b_mat) * scale ----------------
// modes: 1 = bf16 contiguous (applies scale), 6 = fp8 contiguous,
//        2/3 = fp8 kv1 K/V half (row 512B: [K 256B][V 256B] planar),
//        4/5 = fp8 kv2 k/v half (row 256B, interleaved 2B groups)
// Linear grid, COLUMN-FASTEST tile order + bijective XCD-chunked swizzle (m204).
struct GemmOut {
    const float* bias[4];
    void*        out[4];
    int          mode[4];
    float        scale[4];
};

template <int K, int NC, int NTOT>
__global__ __launch_bounds__(256) void gemm_mfma_kernel(const bf16_t* __restrict__ A,
                                                        const bf16_t* __restrict__ Wt,
                                                        GemmOut args) {
    __shared__ __align__(16) char smem[36864];
    bf16_t* As = (bf16_t*)smem;            // [128][64] swizzled = 16 KB
    bf16_t* Bs = (bf16_t*)(smem + 16384);  // [128][64] swizzled = 16 KB

    int t    = threadIdx.x;
    int lane = t & 63;
    int w    = t >> 6;
    int wm   = w >> 1, wn = w & 1;

    // bijective XCD-chunked remap of the linear block id
    int nwg  = gridDim.x;
    int orig = blockIdx.x;
    int q8 = nwg >> 3, r8 = nwg & 7;
    int xcd = orig & 7, j8 = orig >> 3;
    int wg = (xcd < r8 ? xcd * (q8 + 1) : r8 * (q8 + 1) + (xcd - r8) * q8) + j8;
    const int NY = NTOT / 128;             // col-blocks per row-panel
    int tile_r = (wg / NY) * 128;
    int tile_c = (wg % NY) * 128;          // fastest-varying within an XCD chunk
    int mat = tile_c / NC;
    int tcl = tile_c % NC;

    int rl = lane >> 3;            // local row 0..7 within an 8-row group
    int sc = (lane & 7) ^ rl;      // which data chunk this lane must fetch

    floatx4 acc[4][4] = {};

    for (int kk = 0; kk < K; kk += 64) {
        #pragma unroll
        for (int j = 0; j < 4; j++) {
            int q = w * 4 + j;     // 8-row group 0..15
            const bf16_t* ga = &A [(size_t)(tile_r + q * 8 + rl) * K + kk + sc * 8];
            const bf16_t* gb = &Wt[(size_t)(tile_c + q * 8 + rl) * K + kk + sc * 8];
            gload_lds16(ga, As + q * 512);
            gload_lds16(gb, Bs + q * 512);
        }
        __syncthreads();
        #pragma unroll
        for (int kh = 0; kh < 64; kh += 32) {
            int sw = (((kh >> 3) + (lane >> 4)) ^ (lane & 7)) << 3;  // swizzled chunk offset
            bf16x8 af[4], bfr[4];
            #pragma unroll
            for (int mi = 0; mi < 4; mi++)
                af[mi] = *(const bf16x8*)&As[(wm * 64 + mi * 16 + (lane & 15)) * 64 + sw];
            #pragma unroll
            for (int ni = 0; ni < 4; ni++)
                bfr[ni] = *(const bf16x8*)&Bs[(wn * 64 + ni * 16 + (lane & 15)) * 64 + sw];
            #pragma unroll
            for (int mi = 0; mi < 4; mi++)
                #pragma unroll
                for (int ni = 0; ni < 4; ni++)
                    acc[mi][ni] = __builtin_amdgcn_mfma_f32_16x16x32_bf16(af[mi], bfr[ni], acc[mi][ni], 0, 0, 0);
        }
        __syncthreads();
    }

    // ---- LDS-staged coalesced epilogue ----
    const float* bias = args.bias[mat];
    void* op   = args.out[mat];
    int   mode = args.mode[mat];
    float scl  = args.scale[mat];
    float bv[4];
    #pragma unroll
    for (int ni = 0; ni < 4; ni++) bv[ni] = bias[tcl + wn * 64 + ni * 16 + (lane & 15)];

    if (mode == 1) {
        bf16_t (*Ct)[136] = (bf16_t(*)[136])smem;
        #pragma unroll
        for (int mi = 0; mi < 4; mi++)
            #pragma unroll
            for (int r = 0; r < 4; r++) {
                int row = wm * 64 + mi * 16 + (lane >> 4) * 4 + r;
                #pragma unroll
                for (int ni = 0; ni < 4; ni++) {
                    int col = wn * 64 + ni * 16 + (lane & 15);
                    Ct[row][col] = (bf16_t)((acc[mi][ni][r] + bv[ni]) * scl);
                }
            }
        __syncthreads();
        bf16_t* o = (bf16_t*)op;
        #pragma unroll
        for (int it = 0; it < 8; it++) {
            int idx = t + it * 256;
            int row = idx >> 4;
            int cg  = idx & 15;
            int gr = tile_r + row;
            if (gr < NNODES)
                *(int4*)(o + (size_t)gr * NC + tcl + cg * 8) = *(int4*)&Ct[row][cg * 8];
        }
    } else {
        u8 (*Ct8)[136] = (u8(*)[136])smem;
        #pragma unroll
        for (int mi = 0; mi < 4; mi++)
            #pragma unroll
            for (int r = 0; r < 4; r++) {
                int row = wm * 64 + mi * 16 + (lane >> 4) * 4 + r;
                #pragma unroll
                for (int ni = 0; ni < 4; ni++) {
                    int col = wn * 64 + ni * 16 + (lane & 15);
                    float val = acc[mi][ni][r] + bv[ni];
                    Ct8[row][col] = (u8)(__builtin_amdgcn_cvt_pk_fp8_f32(val, val, 0, false) & 0xff);
                }
            }
        __syncthreads();
        u8* o = (u8*)op;
        if (mode == 6) {
            #pragma unroll
            for (int it = 0; it < 16; it++) {
                int idx = t + it * 256;
                int row = idx >> 5;
                int cg  = idx & 31;
                int gr = tile_r + row;
                if (gr < NNODES) {
                    unsigned v4 = *(unsigned*)&Ct8[row][cg * 4];
                    *(unsigned*)(o + (size_t)gr * NC + tcl + cg * 4) = v4;
                }
            }
        } else if (mode <= 3) {
            // planar kv1: row = [K fp8 x256][V fp8 x256]
            int koff = (mode == 2) ? 0 : 256;
            #pragma unroll
            for (int it = 0; it < 16; it++) {
                int idx = t + it * 256;
                int row = idx >> 5;
                int cg  = idx & 31;
                int gr = tile_r + row;
                if (gr < NNODES) {
                    unsigned v4 = *(unsigned*)&Ct8[row][cg * 4];
                    *(unsigned*)(o + (size_t)gr * 512 + koff + tcl + cg * 4) = v4;
                }
            }
        } else {
            bool isK = (mode == 4);
            #pragma unroll
            for (int it = 0; it < 32; it++) {
                int idx = t + it * 256;
                int row = idx >> 6;
                int g   = idx & 63;
                int gr = tile_r + row;
                if (gr < NNODES) {
                    unsigned short v2 = *(unsigned short*)&Ct8[row][g * 2];
                    size_t a = (size_t)gr * 256 + (size_t)((tcl >> 1) + g) * 4 + (isK ? 0 : 2);
                    *(unsigned short*)(o + a) = v2;
                }
            }
        }
    }
}

// ---- attention layer 1 (heads=4, d=64): ONE WAVE PER NODE, 16 edges/body ----
// lane = (quad = edge slot 0..3, sub = 16-channel slice 0..15). 16ch never
// straddles a head (64ch) boundary, so the per-head logit reduce is just
// xor1+xor2 over subs — both pure quad_perm DPP adds.
// STATIC 4-deep buffer pipeline; launched as TWO HALF-NODE dispatches so the
// rocprof top-5 table is not monopolized by a single 64us kernel (diagnostic).
__device__ __forceinline__ float qdot16(const uint4& kw, const floatx2* qf) {
    floatx2 p0 = __builtin_amdgcn_cvt_pk_f32_fp8((int)kw.x, false) * qf[0];
    floatx2 p1 = __builtin_amdgcn_cvt_pk_f32_fp8((int)kw.x, true)  * qf[1];
    p0 += __builtin_amdgcn_cvt_pk_f32_fp8((int)kw.y, false) * qf[2];
    p1 += __builtin_amdgcn_cvt_pk_f32_fp8((int)kw.y, true)  * qf[3];
    p0 += __builtin_amdgcn_cvt_pk_f32_fp8((int)kw.z, false) * qf[4];
    p1 += __builtin_amdgcn_cvt_pk_f32_fp8((int)kw.z, true)  * qf[5];
    p0 += __builtin_amdgcn_cvt_pk_f32_fp8((int)kw.w, false) * qf[6];
    p1 += __builtin_amdgcn_cvt_pk_f32_fp8((int)kw.w, true)  * qf[7];
    floatx2 ps = p0 + p1;
    return ps.x + ps.y;
}

__device__ __forceinline__ void vacc16(const uint4& vw, float pe, float& l, floatx2* a2) {
    floatx2 pv; pv.x = pe; pv.y = pe;
    l += pe;
    a2[0] += pv * __builtin_amdgcn_cvt_pk_f32_fp8((int)vw.x, false);
    a2[1] += pv * __builtin_amdgcn_cvt_pk_f32_fp8((int)vw.x, true);
    a2[2] += pv * __builtin_amdgcn_cvt_pk_f32_fp8((int)vw.y, false);
    a2[3] += pv * __builtin_amdgcn_cvt_pk_f32_fp8((int)vw.y, true);
    a2[4] += pv * __builtin_amdgcn_cvt_pk_f32_fp8((int)vw.z, false);
    a2[5] += pv * __builtin_amdgcn_cvt_pk_f32_fp8((int)vw.z, true);
    a2[6] += pv * __builtin_amdgcn_cvt_pk_f32_fp8((int)vw.w, false);
    a2[7] += pv * __builtin_amdgcn_cvt_pk_f32_fp8((int)vw.w, true);
}

__global__ void attn1_kernel(const bf16_t* __restrict__ q, const u8* __restrict__ kv,
                             const u8* __restrict__ skipf8,
                             const int* __restrict__ row_ptr, const int* __restrict__ esrc,
                             bf16_t* __restrict__ hout, int nbase) {
    int n = nbase + blockIdx.x * 4 + (threadIdx.x >> 6);
    int lane = threadIdx.x & 63;
    int quad = lane >> 4;      // edge slot
    int sub  = lane & 15;      // channel group: ch [16*sub, 16*sub+16)
    size_t qoff = (size_t)n * 256 + sub * 16;

    int beg = row_ptr[n], end = row_ptr[n + 1];

    uint4 qa = *(const uint4*)(q + qoff);
    uint4 qb = *(const uint4*)(q + qoff + 8);
    unsigned qw[8] = {qa.x, qa.y, qa.z, qa.w, qb.x, qb.y, qb.z, qb.w};
    floatx2 qf[8];
    #pragma unroll
    for (int j = 0; j < 8; j++) { qf[j].x = bf_lo(qw[j]); qf[j].y = bf_hi(qw[j]); }

    float l = 0.f;
    floatx2 a2[8] = {};

    if (beg < end) {
        int last = end - 1;
        // prologue: fill 4 static buffers (groups 0..3) + indices for groups 4..7
        int s0 = esrc[min(beg + quad,      last)];
        int s1 = esrc[min(beg + 4 + quad,  last)];
        int s2 = esrc[min(beg + 8 + quad,  last)];
        int s3 = esrc[min(beg + 12 + quad, last)];
        const u8* p0 = kv + (size_t)s0 * 512 + sub * 16;
        const u8* p1 = kv + (size_t)s1 * 512 + sub * 16;
        const u8* p2 = kv + (size_t)s2 * 512 + sub * 16;
        const u8* p3 = kv + (size_t)s3 * 512 + sub * 16;
        uint4 kw0 = *(const uint4*)p0;  uint4 vw0 = *(const uint4*)(p0 + 256);
        uint4 kw1 = *(const uint4*)p1;  uint4 vw1 = *(const uint4*)(p1 + 256);
        uint4 kw2 = *(const uint4*)p2;  uint4 vw2 = *(const uint4*)(p2 + 256);
        uint4 kw3 = *(const uint4*)p3;  uint4 vw3 = *(const uint4*)(p3 + 256);
        s0 = esrc[min(beg + 16 + quad, last)];
        s1 = esrc[min(beg + 20 + quad, last)];
        s2 = esrc[min(beg + 24 + quad, last)];
        s3 = esrc[min(beg + 28 + quad, last)];

        for (int i = beg; i < end; i += 16) {
            float p, pe;
            // slot 0: edges i..i+3
            p = qdot16(kw0, qf);
            p = dpp_radd<0xB1>(p);  p = dpp_radd<0x4E>(p);
            pe = __expf(p);
            pe = (i + quad < end) ? pe : 0.f;
            vacc16(vw0, pe, l, a2);
            { const u8* np = kv + (size_t)s0 * 512 + sub * 16;
              kw0 = *(const uint4*)np;  vw0 = *(const uint4*)(np + 256);
              s0 = esrc[min(i + 32 + quad, last)]; }
            // slot 1: edges i+4..i+7
            p = qdot16(kw1, qf);
            p = dpp_radd<0xB1>(p);  p = dpp_radd<0x4E>(p);
            pe = __expf(p);
            pe = (i + 4 + quad < end) ? pe : 0.f;
            vacc16(vw1, pe, l, a2);
            { const u8* np = kv + (size_t)s1 * 512 + sub * 16;
              kw1 = *(const uint4*)np;  vw1 = *(const uint4*)(np + 256);
              s1 = esrc[min(i + 36 + quad, last)]; }
            // slot 2: edges i+8..i+11
            p = qdot16(kw2, qf);
            p = dpp_radd<0xB1>(p);  p = dpp_radd<0x4E>(p);
            pe = __expf(p);
            pe = (i + 8 + quad < end) ? pe : 0.f;
            vacc16(vw2, pe, l, a2);
            { const u8* np = kv + (size_t)s2 * 512 + sub * 16;
              kw2 = *(const uint4*)np;  vw2 = *(const uint4*)(np + 256);
              s2 = esrc[min(i + 40 + quad, last)]; }
            // slot 3: edges i+12..i+15
            p = qdot16(kw3, qf);
            p = dpp_radd<0xB1>(p);  p = dpp_radd<0x4E>(p);
            pe = __expf(p);
            pe = (i + 12 + quad < end) ? pe : 0.f;
            vacc16(vw3, pe, l, a2);
            { const u8* np = kv + (size_t)s3 * 512 + sub * 16;
              kw3 = *(const uint4*)np;  vw3 = *(const uint4*)(np + 256);
              s3 = esrc[min(i + 44 + quad, last)]; }
        }
    }

    // cross-quad (edge-slot) reduction: xor16 + xor32
    l += __shfl_xor(l, 16, 64);
    l += __shfl_xor(l, 32, 64);
    #pragma unroll
    for (int j = 0; j < 8; j++) {
        a2[j].x += __shfl_xor(a2[j].x, 16, 64);
        a2[j].y += __shfl_xor(a2[j].y, 16, 64);
        a2[j].x += __shfl_xor(a2[j].x, 32, 64);
        a2[j].y += __shfl_xor(a2[j].y, 32, 64);
    }

    if (quad == 0) {
        float inv = (l > 0.f) ? 1.f / l : 0.f;
        uint4 skw = *(const uint4*)(skipf8 + qoff);
        unsigned sw[4] = {skw.x, skw.y, skw.z, skw.w};
        bf16_t r[16];
        #pragma unroll
        for (int j = 0; j < 4; j++) {
            floatx2 lo = __builtin_amdgcn_cvt_pk_f32_fp8((int)sw[j], false);
            floatx2 hi = __builtin_amdgcn_cvt_pk_f32_fp8((int)sw[j], true);
            r[j * 4 + 0] = (bf16_t)fmaxf(lo.x + a2[j * 2].x * inv, 0.f);
            r[j * 4 + 1] = (bf16_t)fmaxf(lo.y + a2[j * 2].y * inv, 0.f);
            r[j * 4 + 2] = (bf16_t)fmaxf(hi.x + a2[j * 2 + 1].x * inv, 0.f);
            r[j * 4 + 3] = (bf16_t)fmaxf(hi.y + a2[j * 2 + 1].y * inv, 0.f);
        }
        *(uint4*)(hout + qoff)     = *(uint4*)r;
        *(uint4*)(hout + qoff + 8) = *(uint4*)(r + 8);
    }
}

// ---- attention layer 2 (heads=1, d=128): ONE WAVE PER NODE, 4 edges/iter ----
// R5 form (2-deep): best measured for degree~16 rows.
__device__ __forceinline__ void attn2_step(uint4 kvv, bool valid, const float* qf,
                                           float& l, float* a) {
    floatx2 k01 = __builtin_amdgcn_cvt_pk_f32_fp8((int)kvv.x, false);
    floatx2 k23 = __builtin_amdgcn_cvt_pk_f32_fp8((int)kvv.y, false);
    floatx2 k45 = __builtin_amdgcn_cvt_pk_f32_fp8((int)kvv.z, false);
    floatx2 k67 = __builtin_amdgcn_cvt_pk_f32_fp8((int)kvv.w, false);
    float p = qf[0] * k01.x + qf[1] * k01.y + qf[2] * k23.x + qf[3] * k23.y
            + qf[4] * k45.x + qf[5] * k45.y + qf[6] * k67.x + qf[7] * k67.y;
    // all-DPP 16-lane reduce: xor1, xor2 (quad_perm), then quad-rotations
    p = dpp_radd<0xB1>(p);
    p = dpp_radd<0x4E>(p);
    p = dpp_radd<0x124>(p);  // row_ror:4  (quad-constant values -> sum-correct)
    p = dpp_radd<0x128>(p);  // row_ror:8
    p = valid ? p : -INFINITY;
    float pe = __expf(p);
    floatx2 v01 = __builtin_amdgcn_cvt_pk_f32_fp8((int)kvv.x, true);
    floatx2 v23 = __builtin_amdgcn_cvt_pk_f32_fp8((int)kvv.y, true);
    floatx2 v45 = __builtin_amdgcn_cvt_pk_f32_fp8((int)kvv.z, true);
    floatx2 v67 = __builtin_amdgcn_cvt_pk_f32_fp8((int)kvv.w, true);
    l    += pe;
    a[0] += pe * v01.x;
    a[1] += pe * v01.y;
    a[2] += pe * v23.x;
    a[3] += pe * v23.y;
    a[4] += pe * v45.x;
    a[5] += pe * v45.y;
    a[6] += pe * v67.x;
    a[7] += pe * v67.y;
}

__global__ void attn2_kernel(const bf16_t* __restrict__ q, const u8* __restrict__ kv,
                             const int* __restrict__ row_ptr, const int* __restrict__ esrc,
                             bf16_t* __restrict__ h2) {
    int n = blockIdx.x * 4 + (threadIdx.x >> 6);
    int lane = threadIdx.x & 63;
    int quad = lane >> 4;
    int sub  = lane & 15;
    int d0 = sub * 8;
    size_t lb = (size_t)(sub * 16);

    int beg = row_ptr[n], end = row_ptr[n + 1];

    uint4 qu = *(const uint4*)(q + (size_t)n * 128 + d0);
    float qf[8] = {bf_lo(qu.x), bf_hi(qu.x), bf_lo(qu.y), bf_hi(qu.y),
                   bf_lo(qu.z), bf_hi(qu.z), bf_lo(qu.w), bf_hi(qu.w)};

    float l = 0.f, a[8] = {};

    if (beg < end) {
        int last = end - 1;
        int s0 = esrc[min(beg + quad,      last)];
        int s1 = esrc[min(beg + 4 + quad,  last)];
        int s2 = esrc[min(beg + 8 + quad,  last)];
        uint4 k0 = *(const uint4*)(kv + (size_t)s0 * 256 + lb);
        uint4 k1 = *(const uint4*)(kv + (size_t)s1 * 256 + lb);

        for (int i = beg; i < end; i += 4) {
            uint4 k2 = *(const uint4*)(kv + (size_t)s2 * 256 + lb);
            s2 = esrc[min(i + 12 + quad, last)];

            attn2_step(k0, i + quad < end, qf, l, a);
            k0 = k1;
            k1 = k2;
        }
    }

    l += __shfl_xor(l, 16, 64);
    l += __shfl_xor(l, 32, 64);
    #pragma unroll
    for (int j = 0; j < 8; j++) {
        a[j] += __shfl_xor(a[j], 16, 64);
        a[j] += __shfl_xor(a[j], 32, 64);
    }
    float inv = (l > 0.f) ? 1.f / l : 0.f;
    if (quad == 0) {
        size_t o = (size_t)n * 128 + d0;
        uint4 cur = *(const uint4*)(h2 + o);
        float cf[8] = {bf_lo(cur.x), bf_hi(cur.x), bf_lo(cur.y), bf_hi(cur.y),
                       bf_lo(cur.z), bf_hi(cur.z), bf_lo(cur.w), bf_hi(cur.w)};
        bf16_t rr[8];
        #pragma unroll
        for (int j = 0; j < 8; j++) rr[j] = (bf16_t)(cf[j] + a[j] * inv);
        *(uint4*)(h2 + o) = *(uint4*)rr;
    }
}

// ---------------- final column mean over nodes (bf16 h2) ----------------
__global__ void colmean_kernel(const bf16_t* __restrict__ h2, float* __restrict__ out) {
    int t = threadIdx.x;
    int c2 = t & 63;
    int grp = t >> 6;
    float s0 = 0.f, s1 = 0.f;
    for (int n = blockIdx.x * 4 + grp; n < NNODES; n += gridDim.x * 4) {
        unsigned u = *((const unsigned*)(h2 + (size_t)n * 128) + c2);
        s0 += bf_lo(u);
        s1 += bf_hi(u);
    }
    __shared__ float red[256][2];
    red[t][0] = s0; red[t][1] = s1;
    __syncthreads();
    if (grp == 0) {
        float t0 = red[c2][0] + red[c2 + 64][0] + red[c2 + 128][0] + red[c2 + 192][0];
        float t1 = red[c2][1] + red[c2 + 64][1] + red[c2 + 128][1] + red[c2 + 192][1];
        atomicAdd(&out[2 * c2],     t0 * (1.0f / NNODES));
        atomicAdd(&out[2 * c2 + 1], t1 * (1.0f / NNODES));
    }
}

extern "C" void kernel_launch(void* const* d_in, const int* in_sizes, int n_in,
                              void* d_out, int out_size, void* d_ws, size_t ws_size,
                              hipStream_t stream) {
    const float* x  = (const float*)d_in[0];
    const int*   ei = (const int*)d_in[1];   // int32: [2, E]
    const int* src = ei;
    const int* dst = ei + NEDGES;

    const float* Wq1 = (const float*)d_in[2];  const float* bq1 = (const float*)d_in[3];
    const float* Wk1 = (const float*)d_in[4];  const float* bk1 = (const float*)d_in[5];
    const float* Wv1 = (const float*)d_in[6];  const float* bv1 = (const float*)d_in[7];
    const float* Ws1 = (const float*)d_in[8];  const float* bs1 = (const float*)d_in[9];
    const float* Wq2 = (const float*)d_in[10]; const float* bq2 = (const float*)d_in[11];
    const float* Wk2 = (const float*)d_in[12]; const float* bk2 = (const float*)d_in[13];
    const float* Wv2 = (const float*)d_in[14]; const float* bv2 = (const float*)d_in[15];
    const float* Ws2 = (const float*)d_in[16]; const float* bs2 = (const float*)d_in[17];

    float* out = (float*)d_out;

    // ---- workspace layout (byte offsets, 16B-aligned) ----
    char* ws = (char*)d_ws;
    bf16_t* q1    = (bf16_t*)(ws);                 // N*256 bf16  = 25,600,000
    u8*     kv1   = (u8*)(ws + 25600000);          // N*512 fp8   = 25,600,000
    u8*     hskip = (u8*)(ws + 51200000);          // N*256 fp8   = 12,800,000
    bf16_t* hbf   = (bf16_t*)(ws + 64000000);      // MPAD*256 bf16 = 25,624,576
    bf16_t* xbf   = (bf16_t*)(ws + 89624576);      // MPAD*128 bf16 = 12,812,288
    bf16_t* wt1   = (bf16_t*)(ws + 102436864);     // 262,144
    bf16_t* wt2   = (bf16_t*)(ws + 102699008);     // 262,144
    int* deg     = (int*)(ws + 102961152);         // N
    int* row_ptr = deg + NNODES;                   // N+1
    int* esrc    = row_ptr + NNODES + 1;           // E
    int* pack    = esrc + NEDGES;                  // E
    int* psum    = pack + NEDGES;                  // NBLK
    // layer-2 buffers alias dead layer-1 regions (stream-ordered lifetimes)
    bf16_t* q2  = (bf16_t*)(ws);                   // N*128 bf16 (over q1)
    u8*     kv2 = (u8*)(ws + 12800000);            // N*256 fp8  (over q1 tail)
    bf16_t* h2  = (bf16_t*)(ws + 25600000);        // N*128 bf16 (over kv1)

    hipMemsetAsync(deg, 0, sizeof(int) * NNODES, stream);
    hipMemsetAsync(out, 0, sizeof(float) * 128, stream);
    hipMemsetAsync(hbf + (size_t)NNODES * 256, 0, (size_t)(MPAD - NNODES) * 256 * sizeof(bf16_t), stream);

    W4 w1; w1.W[0] = Wq1; w1.W[1] = Wk1; w1.W[2] = Wv1; w1.W[3] = Ws1;
    W4 w2; w2.W[0] = Wq2; w2.W[1] = Wk2; w2.W[2] = Wv2; w2.W[3] = Ws2;

    // dedicated count kernel (high atomic MLP), then BW-bound prep
    count_kernel<<<CNT2_BLK, 256, 0, stream>>>(dst, deg, pack);
    prep_kernel<<<PREP_XBLK + PREP_TBLK, 256, 0, stream>>>(x, w1, w2, xbf, wt1, wt2);

    // CSR scan (separate kernels, full grid)
    blocksum_kernel<<<NBLK, 256, 0, stream>>>(deg, psum);
    scanpart_kernel<<<1, 256, 0, stream>>>(psum);
    scanfinal_kernel<<<NBLK, 256, 0, stream>>>(deg, psum, row_ptr);

    // atomic-free scatter (full grid)
    scatter_kernel<<<CNT_BLK, 256, 0, stream>>>(src, pack, row_ptr, esrc);

    // layer 1 GEMM: linear grid 391*8 = 3128, col-fastest + XCD swizzle
    GemmOut a1;
    a1.bias[0] = bq1; a1.bias[1] = bk1; a1.bias[2] = bv1; a1.bias[3] = bs1;
    a1.out[0] = q1;   a1.out[1] = kv1;  a1.out[2] = kv1;  a1.out[3] = hskip;
    a1.mode[0] = 1;   a1.mode[1] = 2;   a1.mode[2] = 3;   a1.mode[3] = 6;
    a1.scale[0] = 0.125f; a1.scale[1] = 1.f; a1.scale[2] = 1.f; a1.scale[3] = 1.f;
    gemm_mfma_kernel<128, 256, 1024><<<(MPAD / 128) * 8, 256, 0, stream>>>(xbf, wt1, a1);

    // attn1 in two half-node dispatches (diagnostic split; perf-neutral)
    attn1_kernel<<<NNODES / 8, 256, 0, stream>>>(q1, kv1, hskip, row_ptr, esrc, hbf, 0);
    attn1_kernel<<<NNODES / 8, 256, 0, stream>>>(q1, kv1, hskip, row_ptr, esrc, hbf, NNODES / 2);

    // layer 2 GEMM: linear grid 391*4 = 1564
    GemmOut a2;
    a2.bias[0] = bq2; a2.bias[1] = bk2; a2.bias[2] = bv2; a2.bias[3] = bs2;
    a2.out[0] = q2;   a2.out[1] = kv2;  a2.out[2] = kv2;  a2.out[3] = h2;
    a2.mode[0] = 1;   a2.mode[1] = 4;   a2.mode[2] = 5;   a2.mode[3] = 1;
    a2.scale[0] = 0.08838834764831845f; a2.scale[1] = 1.f; a2.scale[2] = 1.f; a2.scale[3] = 1.f;
    gemm_mfma_kernel<256, 128, 512><<<(MPAD / 128) * 4, 256, 0, stream>>>(hbf, wt2, a2);

    attn2_kernel<<<NNODES / 4, 256, 0, stream>>>(q2, kv2, row_ptr, esrc, h2);

    colmean_kernel<<<256, 256, 0, stream>>>(h2, out);
}

// Round 10
// 349.473 us; speedup vs baseline: 1.0316x; 1.0316x over previous
//
#include <hip/hip_runtime.h>
#include <math.h>

#define NNODES 50000
#define NEDGES 800000
#define MPAD   50048   // NNODES rounded up to 128
#define NBLK   196     // ceil(NNODES/256)
#define PREP_CNT  1563 // ceil(NEDGES/512): count blocks FIRST (2 edges/thread)
#define PREP_XBLK 3128 // MPAD*128/8/256  (8 floats per thread)
#define PREP_TBLK 64   // 64x64 transpose tiles (32 for wt1, 32 for wt2)
#define CNT_BLK   3125 // NEDGES/256

typedef __bf16 bf16_t;
typedef unsigned char u8;
typedef __attribute__((ext_vector_type(8))) __bf16 bf16x8;
typedef __attribute__((ext_vector_type(4))) float  floatx4;
typedef __attribute__((ext_vector_type(2))) float  floatx2;

__device__ __forceinline__ float bf_lo(unsigned u) { return __uint_as_float(u << 16); }
__device__ __forceinline__ float bf_hi(unsigned u) { return __uint_as_float(u & 0xffff0000u); }

__device__ __forceinline__ void gload_lds16(const bf16_t* g, bf16_t* l) {
    __builtin_amdgcn_global_load_lds(
        (const __attribute__((address_space(1))) unsigned int*)g,
        (__attribute__((address_space(3))) unsigned int*)l, 16, 0, 0);
}

// DPP-based partial-sum: x += x[from dpp_ctrl permutation]; pure VALU (no ds_bpermute).
// 0xB1 = quad_perm[1,0,3,2] (xor1), 0x4E = quad_perm[2,3,0,1] (xor2),
// 0x124 = row_ror:4, 0x128 = row_ror:8 (valid for sums once values are quad-constant).
template <int CTRL>
__device__ __forceinline__ float dpp_radd(float x) {
    int y = __builtin_amdgcn_update_dpp(0, __float_as_int(x), CTRL, 0xf, 0xf, true);
    return x + __int_as_float(y);
}

struct W4 { const float* W[4]; };

// ---- fused prep: COUNT FIRST (atomic latency hides under BW blocks behind it),
// then x cast (8/thread), then LDS-tiled weight transpose.
// LDS 16.9KB caps blocks/CU at 9 > thread-cap 8, so static tile LDS is free.
__global__ void prep_count_kernel(const float* __restrict__ x, W4 w1, W4 w2,
                                  bf16_t* __restrict__ xb, bf16_t* __restrict__ wt1,
                                  bf16_t* __restrict__ wt2,
                                  const int* __restrict__ dst, int* __restrict__ deg,
                                  int* __restrict__ pack) {
    int b = blockIdx.x;
    if (b < PREP_CNT) {
        // 2 independent returning atomics per thread
        int e0 = b * 512 + threadIdx.x;
        int e1 = e0 + 256;
        int d0 = (e0 < NEDGES) ? dst[e0] : -1;
        int d1 = (e1 < NEDGES) ? dst[e1] : -1;
        int o0 = 0, o1 = 0;
        if (d0 >= 0) o0 = atomicAdd(&deg[d0], 1);
        if (d1 >= 0) o1 = atomicAdd(&deg[d1], 1);
        if (d0 >= 0) pack[e0] = (o0 << 16) | d0;    // dst < 50000 < 2^16
        if (d1 >= 0) pack[e1] = (o1 << 16) | d1;
    } else if (b < PREP_CNT + PREP_XBLK) {
        int i = ((b - PREP_CNT) * 256 + threadIdx.x) * 8;  // 8 floats; never straddles a row
        int row = i >> 7;
        bf16_t r[8];
        if (row < NNODES) {
            float4 v0 = *(const float4*)(x + i);
            float4 v1 = *(const float4*)(x + i + 4);
            r[0] = (bf16_t)v0.x; r[1] = (bf16_t)v0.y; r[2] = (bf16_t)v0.z; r[3] = (bf16_t)v0.w;
            r[4] = (bf16_t)v1.x; r[5] = (bf16_t)v1.y; r[6] = (bf16_t)v1.z; r[7] = (bf16_t)v1.w;
        } else {
            #pragma unroll
            for (int j = 0; j < 8; j++) r[j] = (bf16_t)0.f;
        }
        *(uint4*)(xb + i) = *(uint4*)r;
    } else {
        // 64x64 tile transpose via LDS: coalesced reads AND writes
        __shared__ float tile[64][65];
        int tau = b - PREP_CNT - PREP_XBLK;
        const float* Wsrc; bf16_t* dstp; int srcld, dstld, k0, c0;
        if (tau < 32) {            // wt1: four 128x256 matrices -> [c][k]
            int m = tau >> 3, sub = tau & 7;
            k0 = (sub >> 2) * 64;  c0 = (sub & 3) * 64;
            Wsrc = w1.W[m]; srcld = 256;
            dstp = wt1 + (size_t)(m * 256 + c0) * 128 + k0; dstld = 128;
        } else {                   // wt2: four 256x128 matrices -> [c][k]
            int t2 = tau - 32;
            int m = t2 >> 3, sub = t2 & 7;
            k0 = (sub >> 1) * 64;  c0 = (sub & 1) * 64;
            Wsrc = w2.W[m]; srcld = 128;
            dstp = wt2 + (size_t)(m * 128 + c0) * 256 + k0; dstld = 256;
        }
        int wv = threadIdx.x >> 6, ln = threadIdx.x & 63;
        #pragma unroll
        for (int rr = 0; rr < 16; rr++) {
            int row = wv * 16 + rr;
            tile[row][ln] = Wsrc[(size_t)(k0 + row) * srcld + c0 + ln];
        }
        __syncthreads();
        #pragma unroll
        for (int rr = 0; rr < 16; rr++) {
            int col = wv * 16 + rr;
            dstp[(size_t)col * dstld + ln] = (bf16_t)tile[ln][col];   // conflict-free: (ln+col)%32
        }
    }
}

// ---------------- CSR scan (separate kernels, full parallelism) ----------------
__global__ void blocksum_kernel(const int* __restrict__ deg, int* __restrict__ psum) {
    int t = threadIdx.x;
    int i = blockIdx.x * 256 + t;
    int v = (i < NNODES) ? deg[i] : 0;
    __shared__ int s[256];
    s[t] = v;
    __syncthreads();
    for (int off = 128; off; off >>= 1) {
        if (t < off) s[t] += s[t + off];
        __syncthreads();
    }
    if (t == 0) psum[blockIdx.x] = s[0];
}

__global__ void scanpart_kernel(int* __restrict__ psum) {
    __shared__ int s[256];
    int t = threadIdx.x;
    int v = (t < NBLK) ? psum[t] : 0;
    s[t] = v;
    __syncthreads();
    for (int off = 1; off < 256; off <<= 1) {
        int val = (t >= off) ? s[t - off] : 0;
        __syncthreads();
        s[t] += val;
        __syncthreads();
    }
    if (t < NBLK) psum[t] = s[t] - v;   // exclusive
}

__global__ void scanfinal_kernel(const int* __restrict__ deg, const int* __restrict__ psum,
                                 int* __restrict__ row_ptr) {
    int t = threadIdx.x;
    int b = blockIdx.x;
    int i = b * 256 + t;
    int v = (i < NNODES) ? deg[i] : 0;
    __shared__ int s[256];
    s[t] = v;
    __syncthreads();
    for (int off = 1; off < 256; off <<= 1) {
        int val = (t >= off) ? s[t - off] : 0;
        __syncthreads();
        s[t] += val;
        __syncthreads();
    }
    if (i <= NNODES) row_ptr[i] = psum[b] + s[t] - v;  // exclusive prefix
}

// atomic-free scatter: slot = row_ptr[dst] + ordinal
__global__ void scatter_kernel(const int* __restrict__ src, const int* __restrict__ pack,
                               const int* __restrict__ row_ptr, int* __restrict__ esrc) {
    int e = blockIdx.x * 256 + threadIdx.x;
    if (e >= NEDGES) return;
    int p = pack[e];
    int d = p & 0xFFFF;
    int ord = p >> 16;
    esrc[row_ptr[d] + ord] = src[e];
}

// ---------------- bf16 MFMA GEMM: C_mat = (A @ W_mat + b_mat) * scale ----------------
// modes: 1 = bf16 contiguous (applies scale), 6 = fp8 contiguous,
//        2/3 = fp8 kv1 K/V half (row 512B: [K 256B][V 256B] planar),
//        4/5 = fp8 kv2 k/v half (row 256B, interleaved 2B groups)
// Linear grid, COLUMN-FASTEST tile order + bijective XCD-chunked swizzle (m204).
struct GemmOut {
    const float* bias[4];
    void*        out[4];
    int          mode[4];
    float        scale[4];
};

template <int K, int NC, int NTOT>
__global__ __launch_bounds__(256) void gemm_mfma_kernel(const bf16_t* __restrict__ A,
                                                        const bf16_t* __restrict__ Wt,
                                                        GemmOut args) {
    __shared__ __align__(16) char smem[36864];
    bf16_t* As = (bf16_t*)smem;            // [128][64] swizzled = 16 KB
    bf16_t* Bs = (bf16_t*)(smem + 16384);  // [128][64] swizzled = 16 KB

    int t    = threadIdx.x;
    int lane = t & 63;
    int w    = t >> 6;
    int wm   = w >> 1, wn = w & 1;

    // bijective XCD-chunked remap of the linear block id
    int nwg  = gridDim.x;
    int orig = blockIdx.x;
    int q8 = nwg >> 3, r8 = nwg & 7;
    int xcd = orig & 7, j8 = orig >> 3;
    int wg = (xcd < r8 ? xcd * (q8 + 1) : r8 * (q8 + 1) + (xcd - r8) * q8) + j8;
    const int NY = NTOT / 128;             // col-blocks per row-panel
    int tile_r = (wg / NY) * 128;
    int tile_c = (wg % NY) * 128;          // fastest-varying within an XCD chunk
    int mat = tile_c / NC;
    int tcl = tile_c % NC;

    int rl = lane >> 3;            // local row 0..7 within an 8-row group
    int sc = (lane & 7) ^ rl;      // which data chunk this lane must fetch

    floatx4 acc[4][4] = {};

    for (int kk = 0; kk < K; kk += 64) {
        #pragma unroll
        for (int j = 0; j < 4; j++) {
            int q = w * 4 + j;     // 8-row group 0..15
            const bf16_t* ga = &A [(size_t)(tile_r + q * 8 + rl) * K + kk + sc * 8];
            const bf16_t* gb = &Wt[(size_t)(tile_c + q * 8 + rl) * K + kk + sc * 8];
            gload_lds16(ga, As + q * 512);
            gload_lds16(gb, Bs + q * 512);
        }
        __syncthreads();
        #pragma unroll
        for (int kh = 0; kh < 64; kh += 32) {
            int sw = (((kh >> 3) + (lane >> 4)) ^ (lane & 7)) << 3;  // swizzled chunk offset
            bf16x8 af[4], bfr[4];
            #pragma unroll
            for (int mi = 0; mi < 4; mi++)
                af[mi] = *(const bf16x8*)&As[(wm * 64 + mi * 16 + (lane & 15)) * 64 + sw];
            #pragma unroll
            for (int ni = 0; ni < 4; ni++)
                bfr[ni] = *(const bf16x8*)&Bs[(wn * 64 + ni * 16 + (lane & 15)) * 64 + sw];
            #pragma unroll
            for (int mi = 0; mi < 4; mi++)
                #pragma unroll
                for (int ni = 0; ni < 4; ni++)
                    acc[mi][ni] = __builtin_amdgcn_mfma_f32_16x16x32_bf16(af[mi], bfr[ni], acc[mi][ni], 0, 0, 0);
        }
        __syncthreads();
    }

    // ---- LDS-staged coalesced epilogue ----
    const float* bias = args.bias[mat];
    void* op   = args.out[mat];
    int   mode = args.mode[mat];
    float scl  = args.scale[mat];
    float bv[4];
    #pragma unroll
    for (int ni = 0; ni < 4; ni++) bv[ni] = bias[tcl + wn * 64 + ni * 16 + (lane & 15)];

    if (mode == 1) {
        bf16_t (*Ct)[136] = (bf16_t(*)[136])smem;
        #pragma unroll
        for (int mi = 0; mi < 4; mi++)
            #pragma unroll
            for (int r = 0; r < 4; r++) {
                int row = wm * 64 + mi * 16 + (lane >> 4) * 4 + r;
                #pragma unroll
                for (int ni = 0; ni < 4; ni++) {
                    int col = wn * 64 + ni * 16 + (lane & 15);
                    Ct[row][col] = (bf16_t)((acc[mi][ni][r] + bv[ni]) * scl);
                }
            }
        __syncthreads();
        bf16_t* o = (bf16_t*)op;
        #pragma unroll
        for (int it = 0; it < 8; it++) {
            int idx = t + it * 256;
            int row = idx >> 4;
            int cg  = idx & 15;
            int gr = tile_r + row;
            if (gr < NNODES)
                *(int4*)(o + (size_t)gr * NC + tcl + cg * 8) = *(int4*)&Ct[row][cg * 8];
        }
    } else {
        u8 (*Ct8)[136] = (u8(*)[136])smem;
        #pragma unroll
        for (int mi = 0; mi < 4; mi++)
            #pragma unroll
            for (int r = 0; r < 4; r++) {
                int row = wm * 64 + mi * 16 + (lane >> 4) * 4 + r;
                #pragma unroll
                for (int ni = 0; ni < 4; ni++) {
                    int col = wn * 64 + ni * 16 + (lane & 15);
                    float val = acc[mi][ni][r] + bv[ni];
                    Ct8[row][col] = (u8)(__builtin_amdgcn_cvt_pk_fp8_f32(val, val, 0, false) & 0xff);
                }
            }
        __syncthreads();
        u8* o = (u8*)op;
        if (mode == 6) {
            #pragma unroll
            for (int it = 0; it < 16; it++) {
                int idx = t + it * 256;
                int row = idx >> 5;
                int cg  = idx & 31;
                int gr = tile_r + row;
                if (gr < NNODES) {
                    unsigned v4 = *(unsigned*)&Ct8[row][cg * 4];
                    *(unsigned*)(o + (size_t)gr * NC + tcl + cg * 4) = v4;
                }
            }
        } else if (mode <= 3) {
            // planar kv1: row = [K fp8 x256][V fp8 x256]
            int koff = (mode == 2) ? 0 : 256;
            #pragma unroll
            for (int it = 0; it < 16; it++) {
                int idx = t + it * 256;
                int row = idx >> 5;
                int cg  = idx & 31;
                int gr = tile_r + row;
                if (gr < NNODES) {
                    unsigned v4 = *(unsigned*)&Ct8[row][cg * 4];
                    *(unsigned*)(o + (size_t)gr * 512 + koff + tcl + cg * 4) = v4;
                }
            }
        } else {
            bool isK = (mode == 4);
            #pragma unroll
            for (int it = 0; it < 32; it++) {
                int idx = t + it * 256;
                int row = idx >> 6;
                int g   = idx & 63;
                int gr = tile_r + row;
                if (gr < NNODES) {
                    unsigned short v2 = *(unsigned short*)&Ct8[row][g * 2];
                    size_t a = (size_t)gr * 256 + (size_t)((tcl >> 1) + g) * 4 + (isK ? 0 : 2);
                    *(unsigned short*)(o + a) = v2;
                }
            }
        }
    }
}

// ---- attention layer 1 (heads=4, d=64): ONE WAVE PER NODE, 16 edges/body ----
// lane = (quad = edge slot 0..3, sub = 16-channel slice 0..15). 16ch never
// straddles a head (64ch) boundary, so the per-head logit reduce is just
// xor1+xor2 over subs — both pure quad_perm DPP adds.
// STATIC 4-deep buffer pipeline (best measured attn1 form, R6: 64.2us).
__device__ __forceinline__ float qdot16(const uint4& kw, const floatx2* qf) {
    floatx2 p0 = __builtin_amdgcn_cvt_pk_f32_fp8((int)kw.x, false) * qf[0];
    floatx2 p1 = __builtin_amdgcn_cvt_pk_f32_fp8((int)kw.x, true)  * qf[1];
    p0 += __builtin_amdgcn_cvt_pk_f32_fp8((int)kw.y, false) * qf[2];
    p1 += __builtin_amdgcn_cvt_pk_f32_fp8((int)kw.y, true)  * qf[3];
    p0 += __builtin_amdgcn_cvt_pk_f32_fp8((int)kw.z, false) * qf[4];
    p1 += __builtin_amdgcn_cvt_pk_f32_fp8((int)kw.z, true)  * qf[5];
    p0 += __builtin_amdgcn_cvt_pk_f32_fp8((int)kw.w, false) * qf[6];
    p1 += __builtin_amdgcn_cvt_pk_f32_fp8((int)kw.w, true)  * qf[7];
    floatx2 ps = p0 + p1;
    return ps.x + ps.y;
}

__device__ __forceinline__ void vacc16(const uint4& vw, float pe, float& l, floatx2* a2) {
    floatx2 pv; pv.x = pe; pv.y = pe;
    l += pe;
    a2[0] += pv * __builtin_amdgcn_cvt_pk_f32_fp8((int)vw.x, false);
    a2[1] += pv * __builtin_amdgcn_cvt_pk_f32_fp8((int)vw.x, true);
    a2[2] += pv * __builtin_amdgcn_cvt_pk_f32_fp8((int)vw.y, false);
    a2[3] += pv * __builtin_amdgcn_cvt_pk_f32_fp8((int)vw.y, true);
    a2[4] += pv * __builtin_amdgcn_cvt_pk_f32_fp8((int)vw.z, false);
    a2[5] += pv * __builtin_amdgcn_cvt_pk_f32_fp8((int)vw.z, true);
    a2[6] += pv * __builtin_amdgcn_cvt_pk_f32_fp8((int)vw.w, false);
    a2[7] += pv * __builtin_amdgcn_cvt_pk_f32_fp8((int)vw.w, true);
}

__global__ void attn1_kernel(const bf16_t* __restrict__ q, const u8* __restrict__ kv,
                             const u8* __restrict__ skipf8,
                             const int* __restrict__ row_ptr, const int* __restrict__ esrc,
                             bf16_t* __restrict__ hout) {
    int n = blockIdx.x * 4 + (threadIdx.x >> 6);
    int lane = threadIdx.x & 63;
    int quad = lane >> 4;      // edge slot
    int sub  = lane & 15;      // channel group: ch [16*sub, 16*sub+16)
    size_t qoff = (size_t)n * 256 + sub * 16;

    int beg = row_ptr[n], end = row_ptr[n + 1];

    uint4 qa = *(const uint4*)(q + qoff);
    uint4 qb = *(const uint4*)(q + qoff + 8);
    unsigned qw[8] = {qa.x, qa.y, qa.z, qa.w, qb.x, qb.y, qb.z, qb.w};
    floatx2 qf[8];
    #pragma unroll
    for (int j = 0; j < 8; j++) { qf[j].x = bf_lo(qw[j]); qf[j].y = bf_hi(qw[j]); }

    float l = 0.f;
    floatx2 a2[8] = {};

    if (beg < end) {
        int last = end - 1;
        // prologue: fill 4 static buffers (groups 0..3) + indices for groups 4..7
        int s0 = esrc[min(beg + quad,      last)];
        int s1 = esrc[min(beg + 4 + quad,  last)];
        int s2 = esrc[min(beg + 8 + quad,  last)];
        int s3 = esrc[min(beg + 12 + quad, last)];
        const u8* p0 = kv + (size_t)s0 * 512 + sub * 16;
        const u8* p1 = kv + (size_t)s1 * 512 + sub * 16;
        const u8* p2 = kv + (size_t)s2 * 512 + sub * 16;
        const u8* p3 = kv + (size_t)s3 * 512 + sub * 16;
        uint4 kw0 = *(const uint4*)p0;  uint4 vw0 = *(const uint4*)(p0 + 256);
        uint4 kw1 = *(const uint4*)p1;  uint4 vw1 = *(const uint4*)(p1 + 256);
        uint4 kw2 = *(const uint4*)p2;  uint4 vw2 = *(const uint4*)(p2 + 256);
        uint4 kw3 = *(const uint4*)p3;  uint4 vw3 = *(const uint4*)(p3 + 256);
        s0 = esrc[min(beg + 16 + quad, last)];
        s1 = esrc[min(beg + 20 + quad, last)];
        s2 = esrc[min(beg + 24 + quad, last)];
        s3 = esrc[min(beg + 28 + quad, last)];

        for (int i = beg; i < end; i += 16) {
            float p, pe;
            // slot 0: edges i..i+3
            p = qdot16(kw0, qf);
            p = dpp_radd<0xB1>(p);  p = dpp_radd<0x4E>(p);
            pe = __expf(p);
            pe = (i + quad < end) ? pe : 0.f;
            vacc16(vw0, pe, l, a2);
            { const u8* np = kv + (size_t)s0 * 512 + sub * 16;
              kw0 = *(const uint4*)np;  vw0 = *(const uint4*)(np + 256);
              s0 = esrc[min(i + 32 + quad, last)]; }
            // slot 1: edges i+4..i+7
            p = qdot16(kw1, qf);
            p = dpp_radd<0xB1>(p);  p = dpp_radd<0x4E>(p);
            pe = __expf(p);
            pe = (i + 4 + quad < end) ? pe : 0.f;
            vacc16(vw1, pe, l, a2);
            { const u8* np = kv + (size_t)s1 * 512 + sub * 16;
              kw1 = *(const uint4*)np;  vw1 = *(const uint4*)(np + 256);
              s1 = esrc[min(i + 36 + quad, last)]; }
            // slot 2: edges i+8..i+11
            p = qdot16(kw2, qf);
            p = dpp_radd<0xB1>(p);  p = dpp_radd<0x4E>(p);
            pe = __expf(p);
            pe = (i + 8 + quad < end) ? pe : 0.f;
            vacc16(vw2, pe, l, a2);
            { const u8* np = kv + (size_t)s2 * 512 + sub * 16;
              kw2 = *(const uint4*)np;  vw2 = *(const uint4*)(np + 256);
              s2 = esrc[min(i + 40 + quad, last)]; }
            // slot 3: edges i+12..i+15
            p = qdot16(kw3, qf);
            p = dpp_radd<0xB1>(p);  p = dpp_radd<0x4E>(p);
            pe = __expf(p);
            pe = (i + 12 + quad < end) ? pe : 0.f;
            vacc16(vw3, pe, l, a2);
            { const u8* np = kv + (size_t)s3 * 512 + sub * 16;
              kw3 = *(const uint4*)np;  vw3 = *(const uint4*)(np + 256);
              s3 = esrc[min(i + 44 + quad, last)]; }
        }
    }

    // cross-quad (edge-slot) reduction: xor16 + xor32
    l += __shfl_xor(l, 16, 64);
    l += __shfl_xor(l, 32, 64);
    #pragma unroll
    for (int j = 0; j < 8; j++) {
        a2[j].x += __shfl_xor(a2[j].x, 16, 64);
        a2[j].y += __shfl_xor(a2[j].y, 16, 64);
        a2[j].x += __shfl_xor(a2[j].x, 32, 64);
        a2[j].y += __shfl_xor(a2[j].y, 32, 64);
    }

    if (quad == 0) {
        float inv = (l > 0.f) ? 1.f / l : 0.f;
        uint4 skw = *(const uint4*)(skipf8 + qoff);
        unsigned sw[4] = {skw.x, skw.y, skw.z, skw.w};
        bf16_t r[16];
        #pragma unroll
        for (int j = 0; j < 4; j++) {
            floatx2 lo = __builtin_amdgcn_cvt_pk_f32_fp8((int)sw[j], false);
            floatx2 hi = __builtin_amdgcn_cvt_pk_f32_fp8((int)sw[j], true);
            r[j * 4 + 0] = (bf16_t)fmaxf(lo.x + a2[j * 2].x * inv, 0.f);
            r[j * 4 + 1] = (bf16_t)fmaxf(lo.y + a2[j * 2].y * inv, 0.f);
            r[j * 4 + 2] = (bf16_t)fmaxf(hi.x + a2[j * 2 + 1].x * inv, 0.f);
            r[j * 4 + 3] = (bf16_t)fmaxf(hi.y + a2[j * 2 + 1].y * inv, 0.f);
        }
        *(uint4*)(hout + qoff)     = *(uint4*)r;
        *(uint4*)(hout + qoff + 8) = *(uint4*)(r + 8);
    }
}

// ---- attention layer 2 (heads=1, d=128): ONE WAVE PER NODE, 4 edges/iter ----
// R5 form (2-deep): best measured for degree~16 rows.
__device__ __forceinline__ void attn2_step(uint4 kvv, bool valid, const float* qf,
                                           float& l, float* a) {
    floatx2 k01 = __builtin_amdgcn_cvt_pk_f32_fp8((int)kvv.x, false);
    floatx2 k23 = __builtin_amdgcn_cvt_pk_f32_fp8((int)kvv.y, false);
    floatx2 k45 = __builtin_amdgcn_cvt_pk_f32_fp8((int)kvv.z, false);
    floatx2 k67 = __builtin_amdgcn_cvt_pk_f32_fp8((int)kvv.w, false);
    float p = qf[0] * k01.x + qf[1] * k01.y + qf[2] * k23.x + qf[3] * k23.y
            + qf[4] * k45.x + qf[5] * k45.y + qf[6] * k67.x + qf[7] * k67.y;
    // all-DPP 16-lane reduce: xor1, xor2 (quad_perm), then quad-rotations
    p = dpp_radd<0xB1>(p);
    p = dpp_radd<0x4E>(p);
    p = dpp_radd<0x124>(p);  // row_ror:4  (quad-constant values -> sum-correct)
    p = dpp_radd<0x128>(p);  // row_ror:8
    p = valid ? p : -INFINITY;
    float pe = __expf(p);
    floatx2 v01 = __builtin_amdgcn_cvt_pk_f32_fp8((int)kvv.x, true);
    floatx2 v23 = __builtin_amdgcn_cvt_pk_f32_fp8((int)kvv.y, true);
    floatx2 v45 = __builtin_amdgcn_cvt_pk_f32_fp8((int)kvv.z, true);
    floatx2 v67 = __builtin_amdgcn_cvt_pk_f32_fp8((int)kvv.w, true);
    l    += pe;
    a[0] += pe * v01.x;
    a[1] += pe * v01.y;
    a[2] += pe * v23.x;
    a[3] += pe * v23.y;
    a[4] += pe * v45.x;
    a[5] += pe * v45.y;
    a[6] += pe * v67.x;
    a[7] += pe * v67.y;
}

__global__ void attn2_kernel(const bf16_t* __restrict__ q, const u8* __restrict__ kv,
                             const int* __restrict__ row_ptr, const int* __restrict__ esrc,
                             bf16_t* __restrict__ h2) {
    int n = blockIdx.x * 4 + (threadIdx.x >> 6);
    int lane = threadIdx.x & 63;
    int quad = lane >> 4;
    int sub  = lane & 15;
    int d0 = sub * 8;
    size_t lb = (size_t)(sub * 16);

    int beg = row_ptr[n], end = row_ptr[n + 1];

    uint4 qu = *(const uint4*)(q + (size_t)n * 128 + d0);
    float qf[8] = {bf_lo(qu.x), bf_hi(qu.x), bf_lo(qu.y), bf_hi(qu.y),
                   bf_lo(qu.z), bf_hi(qu.z), bf_lo(qu.w), bf_hi(qu.w)};

    float l = 0.f, a[8] = {};

    if (beg < end) {
        int last = end - 1;
        int s0 = esrc[min(beg + quad,      last)];
        int s1 = esrc[min(beg + 4 + quad,  last)];
        int s2 = esrc[min(beg + 8 + quad,  last)];
        uint4 k0 = *(const uint4*)(kv + (size_t)s0 * 256 + lb);
        uint4 k1 = *(const uint4*)(kv + (size_t)s1 * 256 + lb);

        for (int i = beg; i < end; i += 4) {
            uint4 k2 = *(const uint4*)(kv + (size_t)s2 * 256 + lb);
            s2 = esrc[min(i + 12 + quad, last)];

            attn2_step(k0, i + quad < end, qf, l, a);
            k0 = k1;
            k1 = k2;
        }
    }

    l += __shfl_xor(l, 16, 64);
    l += __shfl_xor(l, 32, 64);
    #pragma unroll
    for (int j = 0; j < 8; j++) {
        a[j] += __shfl_xor(a[j], 16, 64);
        a[j] += __shfl_xor(a[j], 32, 64);
    }
    float inv = (l > 0.f) ? 1.f / l : 0.f;
    if (quad == 0) {
        size_t o = (size_t)n * 128 + d0;
        uint4 cur = *(const uint4*)(h2 + o);
        float cf[8] = {bf_lo(cur.x), bf_hi(cur.x), bf_lo(cur.y), bf_hi(cur.y),
                       bf_lo(cur.z), bf_hi(cur.z), bf_lo(cur.w), bf_hi(cur.w)};
        bf16_t rr[8];
        #pragma unroll
        for (int j = 0; j < 8; j++) rr[j] = (bf16_t)(cf[j] + a[j] * inv);
        *(uint4*)(h2 + o) = *(uint4*)rr;
    }
}

// ---------------- final column mean over nodes (bf16 h2) ----------------
__global__ void colmean_kernel(const bf16_t* __restrict__ h2, float* __restrict__ out) {
    int t = threadIdx.x;
    int c2 = t & 63;
    int grp = t >> 6;
    float s0 = 0.f, s1 = 0.f;
    for (int n = blockIdx.x * 4 + grp; n < NNODES; n += gridDim.x * 4) {
        unsigned u = *((const unsigned*)(h2 + (size_t)n * 128) + c2);
        s0 += bf_lo(u);
        s1 += bf_hi(u);
    }
    __shared__ float red[256][2];
    red[t][0] = s0; red[t][1] = s1;
    __syncthreads();
    if (grp == 0) {
        float t0 = red[c2][0] + red[c2 + 64][0] + red[c2 + 128][0] + red[c2 + 192][0];
        float t1 = red[c2][1] + red[c2 + 64][1] + red[c2 + 128][1] + red[c2 + 192][1];
        atomicAdd(&out[2 * c2],     t0 * (1.0f / NNODES));
        atomicAdd(&out[2 * c2 + 1], t1 * (1.0f / NNODES));
    }
}

extern "C" void kernel_launch(void* const* d_in, const int* in_sizes, int n_in,
                              void* d_out, int out_size, void* d_ws, size_t ws_size,
                              hipStream_t stream) {
    const float* x  = (const float*)d_in[0];
    const int*   ei = (const int*)d_in[1];   // int32: [2, E]
    const int* src = ei;
    const int* dst = ei + NEDGES;

    const float* Wq1 = (const float*)d_in[2];  const float* bq1 = (const float*)d_in[3];
    const float* Wk1 = (const float*)d_in[4];  const float* bk1 = (const float*)d_in[5];
    const float* Wv1 = (const float*)d_in[6];  const float* bv1 = (const float*)d_in[7];
    const float* Ws1 = (const float*)d_in[8];  const float* bs1 = (const float*)d_in[9];
    const float* Wq2 = (const float*)d_in[10]; const float* bq2 = (const float*)d_in[11];
    const float* Wk2 = (const float*)d_in[12]; const float* bk2 = (const float*)d_in[13];
    const float* Wv2 = (const float*)d_in[14]; const float* bv2 = (const float*)d_in[15];
    const float* Ws2 = (const float*)d_in[16]; const float* bs2 = (const float*)d_in[17];

    float* out = (float*)d_out;

    // ---- workspace layout (byte offsets, 16B-aligned) ----
    char* ws = (char*)d_ws;
    bf16_t* q1    = (bf16_t*)(ws);                 // N*256 bf16  = 25,600,000
    u8*     kv1   = (u8*)(ws + 25600000);          // N*512 fp8   = 25,600,000
    u8*     hskip = (u8*)(ws + 51200000);          // N*256 fp8   = 12,800,000
    bf16_t* hbf   = (bf16_t*)(ws + 64000000);      // MPAD*256 bf16 = 25,624,576
    bf16_t* xbf   = (bf16_t*)(ws + 89624576);      // MPAD*128 bf16 = 12,812,288
    bf16_t* wt1   = (bf16_t*)(ws + 102436864);     // 262,144
    bf16_t* wt2   = (bf16_t*)(ws + 102699008);     // 262,144
    int* deg     = (int*)(ws + 102961152);         // N
    int* row_ptr = deg + NNODES;                   // N+1
    int* esrc    = row_ptr + NNODES + 1;           // E
    int* pack    = esrc + NEDGES;                  // E
    int* psum    = pack + NEDGES;                  // NBLK
    // layer-2 buffers alias dead layer-1 regions (stream-ordered lifetimes)
    bf16_t* q2  = (bf16_t*)(ws);                   // N*128 bf16 (over q1)
    u8*     kv2 = (u8*)(ws + 12800000);            // N*256 fp8  (over q1 tail)
    bf16_t* h2  = (bf16_t*)(ws + 25600000);        // N*128 bf16 (over kv1)

    hipMemsetAsync(deg, 0, sizeof(int) * NNODES, stream);
    hipMemsetAsync(out, 0, sizeof(float) * 128, stream);
    hipMemsetAsync(hbf + (size_t)NNODES * 256, 0, (size_t)(MPAD - NNODES) * 256 * sizeof(bf16_t), stream);

    W4 w1; w1.W[0] = Wq1; w1.W[1] = Wk1; w1.W[2] = Wv1; w1.W[3] = Ws1;
    W4 w2; w2.W[0] = Wq2; w2.W[1] = Wk2; w2.W[2] = Wv2; w2.W[3] = Ws2;

    // fused prep+count: count blocks FIRST so atomic latency hides under BW blocks
    prep_count_kernel<<<PREP_CNT + PREP_XBLK + PREP_TBLK, 256, 0, stream>>>(
        x, w1, w2, xbf, wt1, wt2, dst, deg, pack);

    // CSR scan (separate kernels, full grid)
    blocksum_kernel<<<NBLK, 256, 0, stream>>>(deg, psum);
    scanpart_kernel<<<1, 256, 0, stream>>>(psum);
    scanfinal_kernel<<<NBLK, 256, 0, stream>>>(deg, psum, row_ptr);

    // atomic-free scatter (full grid)
    scatter_kernel<<<CNT_BLK, 256, 0, stream>>>(src, pack, row_ptr, esrc);

    // layer 1 GEMM: linear grid 391*8 = 3128, col-fastest + XCD swizzle
    GemmOut a1;
    a1.bias[0] = bq1; a1.bias[1] = bk1; a1.bias[2] = bv1; a1.bias[3] = bs1;
    a1.out[0] = q1;   a1.out[1] = kv1;  a1.out[2] = kv1;  a1.out[3] = hskip;
    a1.mode[0] = 1;   a1.mode[1] = 2;   a1.mode[2] = 3;   a1.mode[3] = 6;
    a1.scale[0] = 0.125f; a1.scale[1] = 1.f; a1.scale[2] = 1.f; a1.scale[3] = 1.f;
    gemm_mfma_kernel<128, 256, 1024><<<(MPAD / 128) * 8, 256, 0, stream>>>(xbf, wt1, a1);

    attn1_kernel<<<NNODES / 4, 256, 0, stream>>>(q1, kv1, hskip, row_ptr, esrc, hbf);

    // layer 2 GEMM: linear grid 391*4 = 1564
    GemmOut a2;
    a2.bias[0] = bq2; a2.bias[1] = bk2; a2.bias[2] = bv2; a2.bias[3] = bs2;
    a2.out[0] = q2;   a2.out[1] = kv2;  a2.out[2] = kv2;  a2.out[3] = h2;
    a2.mode[0] = 1;   a2.mode[1] = 4;   a2.mode[2] = 5;   a2.mode[3] = 1;
    a2.scale[0] = 0.08838834764831845f; a2.scale[1] = 1.f; a2.scale[2] = 1.f; a2.scale[3] = 1.f;
    gemm_mfma_kernel<256, 128, 512><<<(MPAD / 128) * 4, 256, 0, stream>>>(hbf, wt2, a2);

    attn2_kernel<<<NNODES / 4, 256, 0, stream>>>(q2, kv2, row_ptr, esrc, h2);

    colmean_kernel<<<256, 256, 0, stream>>>(h2, out);
}